// Round 3
// baseline (1289.853 us; speedup 1.0000x reference)
//
#include <hip/hip_runtime.h>
#include <math.h>

// Problem constants (fixed by the reference)
#define BN 16384
#define DN 512
#define KN 16384
#define HN 256
#define ZN 128

// ---------------------------------------------------------------------------
// Encoder: features[B,512] -> Linear(512,256) -> LN -> GELU -> Linear(256,128)
// writes encoded[B][128] fp32. Block = 256 threads, 8 rows per block.
// ---------------------------------------------------------------------------
__global__ __launch_bounds__(256) void enc_kernel(
    const float* __restrict__ feat, const float* __restrict__ W1, const float* __restrict__ b1,
    const float* __restrict__ g1, const float* __restrict__ be1,
    const float* __restrict__ W2, const float* __restrict__ b2,
    float* __restrict__ encoded)
{
    __shared__ float xf[8][512];
    __shared__ float hb[8][256];
    __shared__ float red1[4][8];
    __shared__ float red2[4][8];
    const int tid = threadIdx.x;
    const int rbase = blockIdx.x * 8;

    // stage 8 feature rows (contiguous 4096 fp32 = 16KB), coalesced float4
    {
        const float4* src = (const float4*)(feat + rbase * 512);
        float4* dst = (float4*)&xf[0][0];
        #pragma unroll
        for (int i = 0; i < 4; ++i) dst[tid * 4 + i] = src[tid * 4 + i];
    }
    __syncthreads();

    // GEMM1: t1[r][j], j = tid (H=256 columns)
    const int j = tid;
    float acc[8];
    {
        float bias = b1[j];
        #pragma unroll
        for (int r = 0; r < 8; ++r) acc[r] = bias;
    }
    for (int k = 0; k < 512; k += 4) {
        float w0 = W1[(k + 0) * 256 + j];
        float w1 = W1[(k + 1) * 256 + j];
        float w2 = W1[(k + 2) * 256 + j];
        float w3 = W1[(k + 3) * 256 + j];
        #pragma unroll
        for (int r = 0; r < 8; ++r) {
            float4 x = *((const float4*)&xf[r][k]);
            acc[r] = fmaf(x.x, w0, acc[r]);
            acc[r] = fmaf(x.y, w1, acc[r]);
            acc[r] = fmaf(x.z, w2, acc[r]);
            acc[r] = fmaf(x.w, w3, acc[r]);
        }
    }

    // LayerNorm over H=256 (block-wide reduction), then exact GELU
    float s1[8], s2[8];
    #pragma unroll
    for (int r = 0; r < 8; ++r) { s1[r] = acc[r]; s2[r] = acc[r] * acc[r]; }
    #pragma unroll
    for (int m = 1; m < 64; m <<= 1) {
        #pragma unroll
        for (int r = 0; r < 8; ++r) {
            s1[r] += __shfl_xor(s1[r], m, 64);
            s2[r] += __shfl_xor(s2[r], m, 64);
        }
    }
    const int wave = tid >> 6, lane = tid & 63;
    if (lane == 0) {
        #pragma unroll
        for (int r = 0; r < 8; ++r) { red1[wave][r] = s1[r]; red2[wave][r] = s2[r]; }
    }
    __syncthreads();
    {
        float gg = g1[j], bb = be1[j];
        #pragma unroll
        for (int r = 0; r < 8; ++r) {
            float sum = red1[0][r] + red1[1][r] + red1[2][r] + red1[3][r];
            float ssq = red2[0][r] + red2[1][r] + red2[2][r] + red2[3][r];
            float mu = sum * (1.0f / 256.0f);
            float var = fmaxf(ssq * (1.0f / 256.0f) - mu * mu, 0.0f);
            float rstd = rsqrtf(var + 1e-5f);
            float t = (acc[r] - mu) * rstd * gg + bb;
            hb[r][j] = 0.5f * t * (1.0f + erff(t * 0.70710678118654752f));
        }
    }
    __syncthreads();

    // GEMM2: encoded[r][j2], j2 = tid&127, rows split by tid>>7; direct store
    const int j2 = tid & 127;
    const int rh = tid >> 7;
    float a2[4];
    {
        float bias2 = b2[j2];
        #pragma unroll
        for (int r = 0; r < 4; ++r) a2[r] = bias2;
    }
    for (int k = 0; k < 256; k += 4) {
        float w0 = W2[(k + 0) * 128 + j2];
        float w1 = W2[(k + 1) * 128 + j2];
        float w2v = W2[(k + 2) * 128 + j2];
        float w3 = W2[(k + 3) * 128 + j2];
        #pragma unroll
        for (int r = 0; r < 4; ++r) {
            float4 h = *((const float4*)&hb[rh * 4 + r][k]);
            a2[r] = fmaf(h.x, w0, a2[r]);
            a2[r] = fmaf(h.y, w1, a2[r]);
            a2[r] = fmaf(h.z, w2v, a2[r]);
            a2[r] = fmaf(h.w, w3, a2[r]);
        }
    }
    #pragma unroll
    for (int r = 0; r < 4; ++r)
        encoded[(rbase + rh * 4 + r) * 128 + j2] = a2[r];
}

// ---------------------------------------------------------------------------
// cnorm[k] = ||codebook[k]||^2  (one wave per codebook row)
// ---------------------------------------------------------------------------
__global__ __launch_bounds__(256) void cnorm_kernel(
    const float* __restrict__ cb, float* __restrict__ cnorm)
{
    const int tid = threadIdx.x;
    const int wave = tid >> 6, lane = tid & 63;
    const int row = blockIdx.x * 4 + wave;
    const float2 p = *((const float2*)(cb + row * 128 + lane * 2));
    float s = fmaf(p.x, p.x, p.y * p.y);
    #pragma unroll
    for (int m = 1; m < 64; m <<= 1) s += __shfl_xor(s, m, 64);
    if (lane == 0) cnorm[row] = s;
}

// ---------------------------------------------------------------------------
// Distance + argmin: per block, 64 rows x (K/2) cols in 128-col chunks.
// score = ||c||^2 - 2 x.c (same argmin as sqrt(max(d2,0)); monotone).
// LDS: xs[128z][64rows] 32KB (staged once, in-LDS transpose from encoded)
//      cs[32z][128cols] 16KB (staged per z-quarter, transpose from cb)
// 48KB total. 256 threads, 4x8 micro-tile. First-index tie-break.
// ---------------------------------------------------------------------------
__global__ __launch_bounds__(256) void dist_kernel(
    const float* __restrict__ encoded, const float* __restrict__ cb,
    const float* __restrict__ cnorm,
    float* __restrict__ part_min, int* __restrict__ part_idx)
{
    __shared__ float xs[128][64];   // [z][row]  32 KB
    __shared__ float cs[32][128];   // [z-quarter][col] 16 KB
    const int tid = threadIdx.x;
    const int tx = tid & 15;        // 16 col groups * 8 cols
    const int ty = tid >> 4;        // 16 row groups * 4 rows
    const int btile = blockIdx.x >> 1;
    const int kh = blockIdx.x & 1;
    const int rbase = btile * 64;
    const int kbase = kh * 8192;

    // stage x tile once: thread t covers row (t&63), z-segment of 32 (128B)
    {
        const int row = tid & 63;
        const int zseg = (tid >> 6) * 32;
        const float4* src = (const float4*)(encoded + (rbase + row) * 128 + zseg);
        #pragma unroll
        for (int i = 0; i < 8; ++i) {
            float4 v = src[i];
            xs[zseg + i * 4 + 0][row] = v.x;
            xs[zseg + i * 4 + 1][row] = v.y;
            xs[zseg + i * 4 + 2][row] = v.z;
            xs[zseg + i * 4 + 3][row] = v.w;
        }
    }

    float mv[4]; int mi[4];
    #pragma unroll
    for (int r = 0; r < 4; ++r) { mv[r] = 3.4e38f; mi[r] = 0; }

    const int scol = tid & 127;          // cs staging col (codebook entry)
    const int szseg = (tid >> 7) * 16;   // cs staging z-segment (64B contig)

    for (int kc = 0; kc < 8192; kc += 128) {
        float acc[4][8];
        #pragma unroll
        for (int r = 0; r < 4; ++r)
            #pragma unroll
            for (int c = 0; c < 8; ++c) acc[r][c] = 0.0f;

        for (int zq = 0; zq < 4; ++zq) {
            __syncthreads();
            {   // stage cs: codebook rows kbase+kc+col, z in [zq*32, zq*32+32)
                const float4* src = (const float4*)(cb + (kbase + kc + scol) * 128 + zq * 32 + szseg);
                #pragma unroll
                for (int i = 0; i < 4; ++i) {
                    float4 v = src[i];
                    cs[szseg + i * 4 + 0][scol] = v.x;
                    cs[szseg + i * 4 + 1][scol] = v.y;
                    cs[szseg + i * 4 + 2][scol] = v.z;
                    cs[szseg + i * 4 + 3][scol] = v.w;
                }
            }
            __syncthreads();

            #pragma unroll 4
            for (int z = 0; z < 32; ++z) {
                float4 a = *((const float4*)&xs[zq * 32 + z][ty * 4]);
                float4 b0 = *((const float4*)&cs[z][tx * 8]);
                float4 b1 = *((const float4*)&cs[z][tx * 8 + 4]);
                float av[4] = {a.x, a.y, a.z, a.w};
                float bv[8] = {b0.x, b0.y, b0.z, b0.w, b1.x, b1.y, b1.z, b1.w};
                #pragma unroll
                for (int r = 0; r < 4; ++r)
                    #pragma unroll
                    for (int c = 0; c < 8; ++c)
                        acc[r][c] = fmaf(av[r], bv[c], acc[r][c]);
            }
        }

        const int colbase = kc + tx * 8;
        #pragma unroll
        for (int c = 0; c < 8; ++c) {
            float cn = cnorm[kbase + colbase + c];
            #pragma unroll
            for (int r = 0; r < 4; ++r) {
                float v = fmaf(-2.0f, acc[r][c], cn);
                if (v < mv[r]) { mv[r] = v; mi[r] = colbase + c; }  // strict < keeps first
            }
        }
    }

    // cross-thread (16 col groups) reduce per row, idx tie-break
    __syncthreads();
    float* rv = &cs[0][0];               // 64*16 fp32 = 4KB
    int*   ri = (int*)&cs[8][0];         // next 4KB
    #pragma unroll
    for (int r = 0; r < 4; ++r) {
        rv[(ty * 4 + r) * 16 + tx] = mv[r];
        ri[(ty * 4 + r) * 16 + tx] = mi[r];
    }
    __syncthreads();
    if (tid < 64) {
        float bv = rv[tid * 16]; int bi = ri[tid * 16];
        #pragma unroll
        for (int t = 1; t < 16; ++t) {
            float v = rv[tid * 16 + t]; int ii = ri[tid * 16 + t];
            if (v < bv || (v == bv && ii < bi)) { bv = v; bi = ii; }
        }
        part_min[kh * 16384 + rbase + tid] = bv;
        part_idx[kh * 16384 + rbase + tid] = bi + kbase;
    }
}

// ---------------------------------------------------------------------------
// Decoder: combine the 2 K-half partials, gather codebook row, Linear->LN->
// GELU->Linear, per-row reconstruction MSE + global sum (for `scale`).
// ---------------------------------------------------------------------------
__global__ __launch_bounds__(256) void dec_kernel(
    const float* __restrict__ feat, const float* __restrict__ cb,
    const float* __restrict__ W3, const float* __restrict__ b3,
    const float* __restrict__ g2, const float* __restrict__ be2,
    const float* __restrict__ W4, const float* __restrict__ b4,
    const float* __restrict__ part_min, const int* __restrict__ part_idx,
    float* __restrict__ re_ws, float* __restrict__ sum_ws, int* __restrict__ idx_ws)
{
    __shared__ float qb[8][128];
    __shared__ float dh[8][256];
    __shared__ float red1[4][8];
    __shared__ float red2[4][8];
    __shared__ int idxs[8];
    const int tid = threadIdx.x;
    const int rbase = blockIdx.x * 8;

    if (tid < 8) {
        int b = rbase + tid;
        float m0 = part_min[b];         int i0 = part_idx[b];
        float m1 = part_min[16384 + b]; int i1 = part_idx[16384 + b];
        int sel = (m1 < m0) ? i1 : i0;  // tie -> i0 (the smaller index)
        sel = min(max(sel, 0), KN - 1); // never read OOB even on bad inputs
        idxs[tid] = sel;
        idx_ws[b] = sel;
    }
    __syncthreads();
    {
        int r = tid >> 5, i = (tid & 31) * 4;
        *((float4*)&qb[r][i]) = *((const float4*)(cb + idxs[r] * 128 + i));
    }
    __syncthreads();

    // GEMM3: t3[r][j], j = tid
    const int j = tid;
    float acc[8];
    {
        float bias = b3[j];
        #pragma unroll
        for (int r = 0; r < 8; ++r) acc[r] = bias;
    }
    for (int k = 0; k < 128; k += 4) {
        float w0 = W3[(k + 0) * 256 + j];
        float w1 = W3[(k + 1) * 256 + j];
        float w2 = W3[(k + 2) * 256 + j];
        float w3v = W3[(k + 3) * 256 + j];
        #pragma unroll
        for (int r = 0; r < 8; ++r) {
            float4 q = *((const float4*)&qb[r][k]);
            acc[r] = fmaf(q.x, w0, acc[r]);
            acc[r] = fmaf(q.y, w1, acc[r]);
            acc[r] = fmaf(q.z, w2, acc[r]);
            acc[r] = fmaf(q.w, w3v, acc[r]);
        }
    }

    // LayerNorm + GELU
    float s1[8], s2[8];
    #pragma unroll
    for (int r = 0; r < 8; ++r) { s1[r] = acc[r]; s2[r] = acc[r] * acc[r]; }
    #pragma unroll
    for (int m = 1; m < 64; m <<= 1) {
        #pragma unroll
        for (int r = 0; r < 8; ++r) {
            s1[r] += __shfl_xor(s1[r], m, 64);
            s2[r] += __shfl_xor(s2[r], m, 64);
        }
    }
    const int wave = tid >> 6, lane = tid & 63;
    if (lane == 0) {
        #pragma unroll
        for (int r = 0; r < 8; ++r) { red1[wave][r] = s1[r]; red2[wave][r] = s2[r]; }
    }
    __syncthreads();
    {
        float gg = g2[j], bb = be2[j];
        #pragma unroll
        for (int r = 0; r < 8; ++r) {
            float sum = red1[0][r] + red1[1][r] + red1[2][r] + red1[3][r];
            float ssq = red2[0][r] + red2[1][r] + red2[2][r] + red2[3][r];
            float mu = sum * (1.0f / 256.0f);
            float var = fmaxf(ssq * (1.0f / 256.0f) - mu * mu, 0.0f);
            float rstd = rsqrtf(var + 1e-5f);
            float t = (acc[r] - mu) * rstd * gg + bb;
            dh[r][j] = 0.5f * t * (1.0f + erff(t * 0.70710678118654752f));
        }
    }
    __syncthreads();

    // GEMM4: rec[r][d] for d = tid and tid+256, then squared error vs features
    float a0[8], a1[8];
    {
        float bias0 = b4[tid], bias1 = b4[tid + 256];
        #pragma unroll
        for (int r = 0; r < 8; ++r) { a0[r] = bias0; a1[r] = bias1; }
    }
    for (int k = 0; k < 256; k += 4) {
        float w00 = W4[(k + 0) * 512 + tid];
        float w01 = W4[(k + 0) * 512 + tid + 256];
        float w10 = W4[(k + 1) * 512 + tid];
        float w11 = W4[(k + 1) * 512 + tid + 256];
        float w20 = W4[(k + 2) * 512 + tid];
        float w21 = W4[(k + 2) * 512 + tid + 256];
        float w30 = W4[(k + 3) * 512 + tid];
        float w31 = W4[(k + 3) * 512 + tid + 256];
        #pragma unroll
        for (int r = 0; r < 8; ++r) {
            float4 h = *((const float4*)&dh[r][k]);
            a0[r] = fmaf(h.x, w00, a0[r]); a1[r] = fmaf(h.x, w01, a1[r]);
            a0[r] = fmaf(h.y, w10, a0[r]); a1[r] = fmaf(h.y, w11, a1[r]);
            a0[r] = fmaf(h.z, w20, a0[r]); a1[r] = fmaf(h.z, w21, a1[r]);
            a0[r] = fmaf(h.w, w30, a0[r]); a1[r] = fmaf(h.w, w31, a1[r]);
        }
    }
    float e[8];
    #pragma unroll
    for (int r = 0; r < 8; ++r) {
        float f0 = feat[(rbase + r) * 512 + tid];
        float f1 = feat[(rbase + r) * 512 + tid + 256];
        float d0 = a0[r] - f0, d1 = a1[r] - f1;
        e[r] = d0 * d0 + d1 * d1;
    }
    #pragma unroll
    for (int m = 1; m < 64; m <<= 1) {
        #pragma unroll
        for (int r = 0; r < 8; ++r) e[r] += __shfl_xor(e[r], m, 64);
    }
    if (lane == 0) {
        #pragma unroll
        for (int r = 0; r < 8; ++r) red1[wave][r] = e[r];
    }
    __syncthreads();
    if (tid < 8) {
        float s = (red1[0][tid] + red1[1][tid] + red1[2][tid] + red1[3][tid]) * (1.0f / 512.0f);
        re_ws[rbase + tid] = s;
        atomicAdd(sum_ws, s);
    }
}

// ---------------------------------------------------------------------------
// Finalize: scale = mean(re)+1e-8; MDL bits; write all 4 fp32 outputs.
// ---------------------------------------------------------------------------
__global__ __launch_bounds__(256) void fin_kernel(
    const float* __restrict__ re_ws, const float* __restrict__ sum_ws,
    const int* __restrict__ idx_ws, float* __restrict__ out)
{
    const int i = blockIdx.x * 256 + threadIdx.x;
    const float scale = (*sum_ws) * (1.0f / 16384.0f) + 1e-8f;
    const float re = re_ws[i];
    const float lp = -fabsf(re) / scale - logf(2.0f * scale);
    const float eb = -lp * 1.4426950408889634f;   // -log_prob / ln(2)
    const float tb = 14.0f + eb;                  // log2(K)=14
    const float ratio = 16384.0f / tb;            // D*32 = 16384
    out[i]             = re;
    out[16384 + i]     = ratio;
    out[2 * 16384 + i] = tb;
    out[3 * 16384 + i] = (float)idx_ws[i];
}

// ---------------------------------------------------------------------------
extern "C" void kernel_launch(void* const* d_in, const int* in_sizes, int n_in,
                              void* d_out, int out_size, void* d_ws, size_t ws_size,
                              hipStream_t stream)
{
    const float* feat = (const float*)d_in[0];
    const float* W1   = (const float*)d_in[1];
    const float* b1   = (const float*)d_in[2];
    const float* g1   = (const float*)d_in[3];
    const float* be1  = (const float*)d_in[4];
    const float* W2   = (const float*)d_in[5];
    const float* b2   = (const float*)d_in[6];
    const float* cb   = (const float*)d_in[7];
    const float* W3   = (const float*)d_in[8];
    const float* b3   = (const float*)d_in[9];
    const float* g2   = (const float*)d_in[10];
    const float* be2  = (const float*)d_in[11];
    const float* W4   = (const float*)d_in[12];
    const float* b4   = (const float*)d_in[13];

    char* ws = (char*)d_ws;
    float* encoded  = (float*)ws;                                       // 8 MB
    float* cnorm    = (float*)(ws + (size_t)(8u << 20));                // 64 KB
    float* part_min = (float*)(ws + (size_t)(8u << 20) + (64u << 10));  // 128 KB
    int*   part_idx = (int*)(ws + (size_t)(8u << 20) + (192u << 10));   // 128 KB
    float* re_ws    = (float*)(ws + (size_t)(8u << 20) + (320u << 10)); // 64 KB
    int*   idx_ws   = (int*)(ws + (size_t)(8u << 20) + (384u << 10));   // 64 KB
    float* sum_ws   = (float*)(ws + (size_t)(8u << 20) + (448u << 10)); // 4 B

    hipMemsetAsync(sum_ws, 0, sizeof(float), stream);
    hipMemsetAsync(part_min, 0, (size_t)(256u << 10), stream);  // min+idx

    hipLaunchKernelGGL(enc_kernel,  dim3(BN / 8), dim3(256), 0, stream,
                       feat, W1, b1, g1, be1, W2, b2, encoded);
    hipLaunchKernelGGL(cnorm_kernel, dim3(KN / 4), dim3(256), 0, stream, cb, cnorm);
    hipLaunchKernelGGL(dist_kernel, dim3((BN / 64) * 2), dim3(256), 0, stream,
                       encoded, cb, cnorm, part_min, part_idx);
    hipLaunchKernelGGL(dec_kernel,  dim3(BN / 8), dim3(256), 0, stream,
                       feat, cb, W3, b3, g2, be2, W4, b4,
                       part_min, part_idx, re_ws, sum_ws, idx_ws);
    hipLaunchKernelGGL(fin_kernel,  dim3(BN / 256), dim3(256), 0, stream,
                       re_ws, sum_ws, idx_ws, (float*)d_out);
}